// Round 2
// baseline (792.199 us; speedup 1.0000x reference)
//
#include <hip/hip_runtime.h>
#include <hip/hip_bf16.h>
#include <stdint.h>

typedef __bf16 bf16_t;
typedef bf16_t bf16x8 __attribute__((ext_vector_type(8)));
typedef bf16_t bf16x4 __attribute__((ext_vector_type(4)));
typedef float f32x4 __attribute__((ext_vector_type(4)));

#define NN 10000
#define EE 80000
#define DD 1024
#define LL 2
#define MPAD 10112   /* 79*128 */
#define NEGS 0.2f

#define GLOAD_LDS16(g, l) \
    __builtin_amdgcn_global_load_lds((__attribute__((address_space(1))) void*)(void*)(g), \
                                     (__attribute__((address_space(3))) void*)(l), 16, 0, 0)

// ---------------------------------------------------------------- transpose fp32 -> bf16
__global__ __launch_bounds__(256)
void transpose_1024(const float* __restrict__ src, bf16_t* __restrict__ dstp)
{
    __shared__ float tile[32][33];
    int bx = blockIdx.x, by = blockIdx.y;
    int tx = threadIdx.x & 31, ty = threadIdx.x >> 5;
#pragma unroll
    for (int i = 0; i < 4; ++i)
        tile[ty + i*8][tx] = src[(size_t)(by*32 + ty + i*8)*1024 + bx*32 + tx];
    __syncthreads();
#pragma unroll
    for (int i = 0; i < 4; ++i)
        dstp[(size_t)(bx*32 + ty + i*8)*1024 + by*32 + tx] = (bf16_t)tile[tx][ty + i*8];
}

// ---------------------------------------------------------------- h init (fp32 in, bf16 out)
__global__ __launch_bounds__(256)
void h_init(const float* __restrict__ x, const int* __restrict__ ntypes,
            const float* __restrict__ nte, bf16_t* __restrict__ hbuf)
{
    size_t idx = ((size_t)blockIdx.x*256 + threadIdx.x) * 8;
    if (idx >= (size_t)MPAD*1024) return;
    int n = (int)(idx >> 10);
    int c = (int)(idx & 1023);
    bf16x8 outv;
    if (n < NN) {
        const float* xp = x + (size_t)n*1024 + c;
        int t = ntypes[n];
        const float* ep = nte + (size_t)t*1024 + c;
#pragma unroll
        for (int j = 0; j < 8; ++j) outv[j] = (bf16_t)(xp[j] + ep[j]);
    } else {
#pragma unroll
        for (int j = 0; j < 8; ++j) outv[j] = (bf16_t)0.f;
    }
    *(bf16x8*)(hbuf + idx) = outv;
}

// ---------------------------------------------------------------- CSR build
__global__ void zero_i32(int* p, int n)
{ int i = blockIdx.x*256 + threadIdx.x; if (i < n) p[i] = 0; }

__global__ void hist_k(const int* __restrict__ dsts, int* __restrict__ deg)
{ int e = blockIdx.x*256 + threadIdx.x; if (e < EE) atomicAdd(&deg[dsts[e]], 1); }

__global__ void scan_block(const int* __restrict__ deg, int* __restrict__ inc,
                           int* __restrict__ bsums)
{
    __shared__ int sdata[256];
    int i = blockIdx.x*256 + threadIdx.x;
    int v = (i < NN) ? deg[i] : 0;
    sdata[threadIdx.x] = v;
    __syncthreads();
    for (int d = 1; d < 256; d <<= 1) {
        int t = (threadIdx.x >= d) ? sdata[threadIdx.x - d] : 0;
        __syncthreads();
        sdata[threadIdx.x] += t;
        __syncthreads();
    }
    if (i < NN) inc[i] = sdata[threadIdx.x];
    if (threadIdx.x == 255) bsums[blockIdx.x] = sdata[255];
}

__global__ void scan_sums(int* bsums, int nb)
{
    if (threadIdx.x == 0 && blockIdx.x == 0) {
        int run = 0;
        for (int i = 0; i < nb; ++i) { int v = bsums[i]; bsums[i] = run; run += v; }
    }
}

__global__ void finalize_rp(const int* __restrict__ inc, const int* __restrict__ bsums,
                            int* __restrict__ rp)
{
    int i = blockIdx.x*256 + threadIdx.x;
    if (i < NN) rp[i+1] = inc[i] + bsums[i >> 8];
    if (i == 0) rp[0] = 0;
}

__global__ void copy_i32(const int* __restrict__ a, int* __restrict__ b, int n)
{ int i = blockIdx.x*256 + threadIdx.x; if (i < n) b[i] = a[i]; }

__global__ void fill_csr(const int* __restrict__ dsts, int* __restrict__ cursor,
                         int* __restrict__ sorted_eid)
{
    int e = blockIdx.x*256 + threadIdx.x;
    if (e < EE) {
        int d = dsts[e];
        int pos = atomicAdd(&cursor[d], 1);
        sorted_eid[pos] = e;
    }
}

// ---------------------------------------------------------------- bias pack (fp32 -> fp32)
__global__ void pack_bias(const float* __restrict__ b1, const float* __restrict__ b2,
                          float* __restrict__ outb, int n1, int n2)
{
    int i = blockIdx.x*256 + threadIdx.x;
    if (i < n1) outb[i] = b1[i];
    else if (i < n1 + n2) outb[i] = b2[i - n1];
}

// ---------------------------------------------------------------- M3 = ete @ We  (3x1024 @ 1024x1024, fp32)
__global__ __launch_bounds__(256)
void compute_m3(const float* __restrict__ ete, const float* __restrict__ WeL,
                float* __restrict__ M3)
{
    __shared__ float se[3072];
    int tid = threadIdx.x;
    for (int i = tid; i < 3072; i += 256) se[i] = ete[i];
    __syncthreads();
    int j = blockIdx.x*256 + tid;
    float a0 = 0.f, a1 = 0.f, a2 = 0.f;
    for (int k = 0; k < 1024; ++k) {
        float w = WeL[(size_t)k*1024 + j];
        a0 += se[k]        * w;
        a1 += se[1024 + k] * w;
        a2 += se[2048 + k] * w;
    }
    M3[j] = a0; M3[1024 + j] = a1; M3[2048 + j] = a2;
}

// ---------------------------------------------------------------- GEMM (m97 structure)
// C[M x Ntot] = A[M x K] * BT[Ntot x K]^T + bias ; store OT, rows < storeM
template <typename OT>
__global__ __launch_bounds__(256)
void gemm_bt(const bf16_t* __restrict__ A, const bf16_t* __restrict__ BT,
             const float* __restrict__ bias, OT* __restrict__ Cmat,
             int K, int Ntot, int storeM)
{
    __shared__ __align__(16) bf16_t As[128*32];
    __shared__ __align__(16) bf16_t Bs[128*32];
    const int tid  = threadIdx.x;
    const int wave = tid >> 6;
    const int lane = tid & 63;
    const int m0 = blockIdx.x * 128;
    const int n0 = blockIdx.y * 128;
    const int wm = (wave & 1) * 64;
    const int wn = (wave >> 1) * 64;
    const int quad = lane >> 4;
    const int l16  = lane & 15;
    const int srow = lane >> 2;
    const int skel = (lane & 3) * 8;

    f32x4 acc[4][4];
    f32x4 zero = {0.f, 0.f, 0.f, 0.f};
#pragma unroll
    for (int i = 0; i < 4; ++i)
#pragma unroll
        for (int j = 0; j < 4; ++j) acc[i][j] = zero;

    const bf16_t* aBase = A  + (size_t)(m0 + wave*32 + srow) * K + skel;
    const bf16_t* bBase = BT + (size_t)(n0 + wave*32 + srow) * K + skel;
    bf16_t* asDst = As + (wave*32)*32;
    bf16_t* bsDst = Bs + (wave*32)*32;

    for (int k0 = 0; k0 < K; k0 += 32) {
        GLOAD_LDS16(aBase + k0,                  asDst);
        GLOAD_LDS16(aBase + (size_t)16*K + k0,   asDst + 16*32);
        GLOAD_LDS16(bBase + k0,                  bsDst);
        GLOAD_LDS16(bBase + (size_t)16*K + k0,   bsDst + 16*32);
        __syncthreads();
        bf16x8 af[4], bfr[4];
#pragma unroll
        for (int mi = 0; mi < 4; ++mi)
            af[mi] = *(const bf16x8*)(As + (wm + mi*16 + l16)*32 + quad*8);
#pragma unroll
        for (int ni = 0; ni < 4; ++ni)
            bfr[ni] = *(const bf16x8*)(Bs + (wn + ni*16 + l16)*32 + quad*8);
#pragma unroll
        for (int mi = 0; mi < 4; ++mi)
#pragma unroll
            for (int ni = 0; ni < 4; ++ni)
                acc[mi][ni] = __builtin_amdgcn_mfma_f32_16x16x32_bf16(af[mi], bfr[ni], acc[mi][ni], 0, 0, 0);
        __syncthreads();
    }

#pragma unroll
    for (int mi = 0; mi < 4; ++mi) {
#pragma unroll
        for (int ni = 0; ni < 4; ++ni) {
            int col = n0 + wn + ni*16 + l16;
            float bv = bias[col];
#pragma unroll
            for (int r = 0; r < 4; ++r) {
                int row = m0 + wm + mi*16 + quad*4 + r;
                if (row < storeM)
                    Cmat[(size_t)row * Ntot + col] = (OT)(acc[mi][ni][r] + bv);
            }
        }
    }
}

// ---------------------------------------------------------------- edge logits (real edges)
__global__ __launch_bounds__(256)
void edge_logit(const int* __restrict__ srcs, const int* __restrict__ dsts,
                const int* __restrict__ etype, const bf16_t* __restrict__ XLXR,
                const float* __restrict__ M3, const float* __restrict__ attv,
                float* __restrict__ pbuf)
{
    int e = blockIdx.x * 4 + (threadIdx.x >> 6);
    int lane = threadIdx.x & 63;
    if (e >= EE) return;
    int s = srcs[e], d = dsts[e], t = etype[e];
    int c0 = lane * 16;
    const bf16x8* xl = (const bf16x8*)(XLXR + (size_t)s*2048 + c0);
    const bf16x8* xr = (const bf16x8*)(XLXR + (size_t)d*2048 + 1024 + c0);
    const float*  at = attv + c0;
    const float*  m3 = M3 + t*1024 + c0;
    bf16x8 a0 = xl[0], a1 = xl[1];
    bf16x8 b0 = xr[0], b1 = xr[1];
    float acc = 0.f;
#pragma unroll
    for (int j = 0; j < 8; ++j) {
        float v = (float)a0[j] + (float)b0[j] + m3[j];
        v = (v > 0.f) ? v : NEGS * v;
        acc += v * at[j];
    }
#pragma unroll
    for (int j = 0; j < 8; ++j) {
        float v = (float)a1[j] + (float)b1[j] + m3[8 + j];
        v = (v > 0.f) ? v : NEGS * v;
        acc += v * at[8 + j];
    }
    acc += __shfl_xor(acc, 1);
    acc += __shfl_xor(acc, 2);
    acc += __shfl_xor(acc, 4);
    acc = fminf(fmaxf(acc, -60.f), 60.f);  // no-op for correct data; NaN guard
    if ((lane & 7) == 0) pbuf[(size_t)e*8 + (lane >> 3)] = __expf(acc);
}

// ---------------------------------------------------------------- self-loop logits
__global__ __launch_bounds__(256)
void self_logit(const int* __restrict__ rp, const int* __restrict__ sorted_eid,
                const int* __restrict__ etype, const bf16_t* __restrict__ XLXR,
                const float* __restrict__ M3, const float* __restrict__ attv,
                float* __restrict__ pself)
{
    int node = blockIdx.x * 4 + (threadIdx.x >> 6);
    int lane = threadIdx.x & 63;
    if (node >= NN) return;
    int b = rp[node], en = rp[node + 1];
    float cnt0 = 0.f, cnt1 = 0.f, cnt2 = 0.f;
    for (int i = b + lane; i < en; i += 64) {
        int t = etype[sorted_eid[i]];
        cnt0 += (t == 0) ? 1.f : 0.f;
        cnt1 += (t == 1) ? 1.f : 0.f;
        cnt2 += (t == 2) ? 1.f : 0.f;
    }
#pragma unroll
    for (int m = 1; m < 64; m <<= 1) {
        cnt0 += __shfl_xor(cnt0, m);
        cnt1 += __shfl_xor(cnt1, m);
        cnt2 += __shfl_xor(cnt2, m);
    }
    float deg = cnt0 + cnt1 + cnt2;
    float inv = 1.f / fmaxf(deg, 1.f);
    float w0 = cnt0 * inv, w1 = cnt1 * inv, w2 = cnt2 * inv;
    int c0 = lane * 16;
    const bf16x8* xl = (const bf16x8*)(XLXR + (size_t)node*2048 + c0);
    const bf16x8* xr = (const bf16x8*)(XLXR + (size_t)node*2048 + 1024 + c0);
    const float*  at = attv + c0;
    const float* m0p = M3 + c0;
    const float* m1p = M3 + 1024 + c0;
    const float* m2p = M3 + 2048 + c0;
    bf16x8 a0 = xl[0], a1 = xl[1], b0 = xr[0], b1 = xr[1];
    float acc = 0.f;
#pragma unroll
    for (int j = 0; j < 8; ++j) {
        float ep = w0*m0p[j] + w1*m1p[j] + w2*m2p[j];
        float v = (float)a0[j] + (float)b0[j] + ep;
        v = (v > 0.f) ? v : NEGS * v;
        acc += v * at[j];
    }
#pragma unroll
    for (int j = 0; j < 8; ++j) {
        float ep = w0*m0p[8+j] + w1*m1p[8+j] + w2*m2p[8+j];
        float v = (float)a1[j] + (float)b1[j] + ep;
        v = (v > 0.f) ? v : NEGS * v;
        acc += v * at[8 + j];
    }
    acc += __shfl_xor(acc, 1);
    acc += __shfl_xor(acc, 2);
    acc += __shfl_xor(acc, 4);
    acc = fminf(fmaxf(acc, -60.f), 60.f);  // no-op for correct data; NaN guard
    if ((lane & 7) == 0) pself[(size_t)node*8 + (lane >> 3)] = __expf(acc);
}

// ---------------------------------------------------------------- aggregate + residual (in-place on hbuf)
__global__ __launch_bounds__(256)
void aggregate(const int* __restrict__ rp, const int* __restrict__ sorted_eid,
               const int* __restrict__ srcs, const bf16_t* __restrict__ XLXR,
               const float* __restrict__ pbuf, const float* __restrict__ pself,
               const float* __restrict__ cbias, bf16_t* __restrict__ hbuf)
{
    int node = blockIdx.x;
    int tid = threadIdx.x;
    __shared__ float sden[8];
    int b = rp[node], en = rp[node + 1];
    if (tid < 8) sden[tid] = pself[(size_t)node*8 + tid];
    __syncthreads();
    for (int i = b + tid; i < en; i += 256) {
        int eid = sorted_eid[i];
        const float* pe = pbuf + (size_t)eid*8;
#pragma unroll
        for (int h = 0; h < 8; ++h) atomicAdd(&sden[h], pe[h]);
    }
    __syncthreads();
    int c = tid * 4;
    int head = tid >> 5;
    float ps = pself[(size_t)node*8 + head];
    bf16x4 xs = *(const bf16x4*)(XLXR + (size_t)node*2048 + c);
    float a0 = ps*(float)xs[0], a1 = ps*(float)xs[1], a2 = ps*(float)xs[2], a3 = ps*(float)xs[3];
    for (int i = b; i < en; ++i) {
        int eid = sorted_eid[i];
        int s = srcs[eid];
        float pv = pbuf[(size_t)eid*8 + head];
        bf16x4 xv = *(const bf16x4*)(XLXR + (size_t)s*2048 + c);
        a0 += pv*(float)xv[0]; a1 += pv*(float)xv[1];
        a2 += pv*(float)xv[2]; a3 += pv*(float)xv[3];
    }
    float invd = 1.f / sden[head];
    bf16x4 hv = *(const bf16x4*)(hbuf + (size_t)node*1024 + c);
    const float* cb = cbias + c;
    bf16x4 outv;
    outv[0] = (bf16_t)((float)hv[0] + fmaxf(a0*invd + cb[0], 0.f));
    outv[1] = (bf16_t)((float)hv[1] + fmaxf(a1*invd + cb[1], 0.f));
    outv[2] = (bf16_t)((float)hv[2] + fmaxf(a2*invd + cb[2], 0.f));
    outv[3] = (bf16_t)((float)hv[3] + fmaxf(a3*invd + cb[3], 0.f));
    *(bf16x4*)(hbuf + (size_t)node*1024 + c) = outv;
}

// ---------------------------------------------------------------- launch
extern "C" void kernel_launch(void* const* d_in, const int* in_sizes, int n_in,
                              void* d_out, int out_size, void* d_ws, size_t ws_size,
                              hipStream_t stream)
{
    (void)in_sizes; (void)n_in; (void)out_size; (void)ws_size;
    const float* x     = (const float*)d_in[0];
    const int*   eidx  = (const int*)d_in[1];
    const int*   etype = (const int*)d_in[2];
    const int*   ntyp  = (const int*)d_in[3];
    const float* nte   = (const float*)d_in[4];
    const float* ete   = (const float*)d_in[5];
    const float* Wl    = (const float*)d_in[6];
    const float* bl    = (const float*)d_in[7];
    const float* Wr    = (const float*)d_in[8];
    const float* br    = (const float*)d_in[9];
    const float* We    = (const float*)d_in[10];
    const float* attw  = (const float*)d_in[11];
    const float* cbias = (const float*)d_in[12];
    const float* outW  = (const float*)d_in[13];
    const float* outb  = (const float*)d_in[14];
    const int* srcs = eidx;
    const int* dsts = eidx + EE;

    char* wsp = (char*)d_ws;
    size_t off = 0;
    auto carve = [&](size_t bytes) -> void* {
        void* pp = wsp + off;
        off += (bytes + 255) & ~(size_t)255;
        return pp;
    };
    bf16_t* hbuf  = (bf16_t*)carve((size_t)MPAD*1024*2);
    bf16_t* XLXR  = (bf16_t*)carve((size_t)MPAD*2048*2);
    bf16_t* WT    = (bf16_t*)carve((size_t)LL*2048*1024*2);
    bf16_t* OWT   = (bf16_t*)carve((size_t)1024*1024*2);
    float*  M3    = (float*)carve(3*1024*4);
    float*  biasb = (float*)carve(2048*4);
    float*  pbuf  = (float*)carve((size_t)EE*8*4);
    float*  pself = (float*)carve((size_t)NN*8*4);
    int* deg    = (int*)carve((size_t)NN*4);
    int* rp     = (int*)carve((size_t)(NN+1)*4);
    int* cursor = (int*)carve((size_t)NN*4);
    int* sorted = (int*)carve((size_t)EE*4);
    int* incb   = (int*)carve((size_t)NN*4);
    int* bsums  = (int*)carve(64*4);

    dim3 tgrid(32, 32);
    for (int l = 0; l < LL; ++l) {
        transpose_1024<<<tgrid, 256, 0, stream>>>(Wl + (size_t)l*1024*1024, WT + (size_t)l*2048*1024);
        transpose_1024<<<tgrid, 256, 0, stream>>>(Wr + (size_t)l*1024*1024, WT + (size_t)l*2048*1024 + (size_t)1024*1024);
    }
    transpose_1024<<<tgrid, 256, 0, stream>>>(outW, OWT);

    h_init<<<5056, 256, 0, stream>>>(x, ntyp, nte, hbuf);

    zero_i32<<<40, 256, 0, stream>>>(deg, NN);
    hist_k<<<(EE + 255)/256, 256, 0, stream>>>(dsts, deg);
    scan_block<<<40, 256, 0, stream>>>(deg, incb, bsums);
    scan_sums<<<1, 64, 0, stream>>>(bsums, 40);
    finalize_rp<<<40, 256, 0, stream>>>(incb, bsums, rp);
    copy_i32<<<40, 256, 0, stream>>>(rp, cursor, NN);
    fill_csr<<<(EE + 255)/256, 256, 0, stream>>>(dsts, cursor, sorted);

    for (int l = 0; l < LL; ++l) {
        pack_bias<<<8, 256, 0, stream>>>(bl + l*1024, br + l*1024, biasb, 1024, 1024);
        dim3 ggrid(MPAD/128, 2048/128);
        gemm_bt<bf16_t><<<ggrid, 256, 0, stream>>>(hbuf, WT + (size_t)l*2048*1024, biasb, XLXR, 1024, 2048, MPAD);
        compute_m3<<<4, 256, 0, stream>>>(ete, We + (size_t)l*1024*1024, M3);
        edge_logit<<<EE/4, 256, 0, stream>>>(srcs, dsts, etype, XLXR, M3, attw + l*1024, pbuf);
        self_logit<<<NN/4, 256, 0, stream>>>(rp, sorted, etype, XLXR, M3, attw + l*1024, pself);
        aggregate<<<NN, 256, 0, stream>>>(rp, sorted, srcs, XLXR, pbuf, pself, cbias + l*1024, hbuf);
    }

    pack_bias<<<4, 256, 0, stream>>>(outb, outb, biasb, 1024, 0);
    dim3 fgrid(MPAD/128, 1024/128);
    gemm_bt<float><<<fgrid, 256, 0, stream>>>(hbuf, OWT, biasb, (float*)d_out, 1024, 1024, NN);
}

// Round 3
// 603.279 us; speedup vs baseline: 1.3132x; 1.3132x over previous
//
#include <hip/hip_runtime.h>
#include <hip/hip_bf16.h>
#include <stdint.h>

typedef __bf16 bf16_t;
typedef bf16_t bf16x8 __attribute__((ext_vector_type(8)));
typedef bf16_t bf16x4 __attribute__((ext_vector_type(4)));
typedef float f32x4 __attribute__((ext_vector_type(4)));

#define NN 10000
#define EE 80000
#define DD 1024
#define LL 2
#define MPAD 10112   /* 79*128 */
#define NEGS 0.2f

#define GLOAD_LDS16(g, l) \
    __builtin_amdgcn_global_load_lds((__attribute__((address_space(1))) void*)(void*)(g), \
                                     (__attribute__((address_space(3))) void*)(l), 16, 0, 0)

// ---------------------------------------------------------------- transpose fp32 -> bf16
__global__ __launch_bounds__(256)
void transpose_1024(const float* __restrict__ src, bf16_t* __restrict__ dstp)
{
    __shared__ float tile[32][33];
    int bx = blockIdx.x, by = blockIdx.y;
    int tx = threadIdx.x & 31, ty = threadIdx.x >> 5;
#pragma unroll
    for (int i = 0; i < 4; ++i)
        tile[ty + i*8][tx] = src[(size_t)(by*32 + ty + i*8)*1024 + bx*32 + tx];
    __syncthreads();
#pragma unroll
    for (int i = 0; i < 4; ++i)
        dstp[(size_t)(bx*32 + ty + i*8)*1024 + by*32 + tx] = (bf16_t)tile[tx][ty + i*8];
}

// ---------------------------------------------------------------- h init (fp32 in, bf16 out)
__global__ __launch_bounds__(256)
void h_init(const float* __restrict__ x, const int* __restrict__ ntypes,
            const float* __restrict__ nte, bf16_t* __restrict__ hbuf)
{
    size_t idx = ((size_t)blockIdx.x*256 + threadIdx.x) * 8;
    if (idx >= (size_t)MPAD*1024) return;
    int n = (int)(idx >> 10);
    int c = (int)(idx & 1023);
    bf16x8 outv;
    if (n < NN) {
        const float* xp = x + (size_t)n*1024 + c;
        int t = ntypes[n];
        const float* ep = nte + (size_t)t*1024 + c;
#pragma unroll
        for (int j = 0; j < 8; ++j) outv[j] = (bf16_t)(xp[j] + ep[j]);
    } else {
#pragma unroll
        for (int j = 0; j < 8; ++j) outv[j] = (bf16_t)0.f;
    }
    *(bf16x8*)(hbuf + idx) = outv;
}

// ---------------------------------------------------------------- CSR build
__global__ void zero_i32(int* p, int n)
{ int i = blockIdx.x*256 + threadIdx.x; if (i < n) p[i] = 0; }

__global__ void hist_k(const int* __restrict__ dsts, int* __restrict__ deg)
{ int e = blockIdx.x*256 + threadIdx.x; if (e < EE) atomicAdd(&deg[dsts[e]], 1); }

__global__ void scan_block(const int* __restrict__ deg, int* __restrict__ inc,
                           int* __restrict__ bsums)
{
    __shared__ int sdata[256];
    int i = blockIdx.x*256 + threadIdx.x;
    int v = (i < NN) ? deg[i] : 0;
    sdata[threadIdx.x] = v;
    __syncthreads();
    for (int d = 1; d < 256; d <<= 1) {
        int t = (threadIdx.x >= d) ? sdata[threadIdx.x - d] : 0;
        __syncthreads();
        sdata[threadIdx.x] += t;
        __syncthreads();
    }
    if (i < NN) inc[i] = sdata[threadIdx.x];
    if (threadIdx.x == 255) bsums[blockIdx.x] = sdata[255];
}

__global__ void scan_sums(int* bsums, int nb)
{
    if (threadIdx.x == 0 && blockIdx.x == 0) {
        int run = 0;
        for (int i = 0; i < nb; ++i) { int v = bsums[i]; bsums[i] = run; run += v; }
    }
}

__global__ void finalize_rp(const int* __restrict__ inc, const int* __restrict__ bsums,
                            int* __restrict__ rp)
{
    int i = blockIdx.x*256 + threadIdx.x;
    if (i < NN) rp[i+1] = inc[i] + bsums[i >> 8];
    if (i == 0) rp[0] = 0;
}

__global__ void copy_i32(const int* __restrict__ a, int* __restrict__ b, int n)
{ int i = blockIdx.x*256 + threadIdx.x; if (i < n) b[i] = a[i]; }

// materialize dst-sorted src and type arrays (kills one indirection in the hot loop)
__global__ void fill_csr(const int* __restrict__ srcs, const int* __restrict__ dsts,
                         const int* __restrict__ etype, int* __restrict__ cursor,
                         int* __restrict__ sorted_src, int* __restrict__ sorted_typ)
{
    int e = blockIdx.x*256 + threadIdx.x;
    if (e < EE) {
        int d = dsts[e];
        int pos = atomicAdd(&cursor[d], 1);
        sorted_src[pos] = srcs[e];
        sorted_typ[pos] = etype[e];
    }
}

// ---------------------------------------------------------------- bias pack (fp32 -> fp32)
__global__ void pack_bias(const float* __restrict__ b1, const float* __restrict__ b2,
                          float* __restrict__ outb, int n1, int n2)
{
    int i = blockIdx.x*256 + threadIdx.x;
    if (i < n1) outb[i] = b1[i];
    else if (i < n1 + n2) outb[i] = b2[i - n1];
}

// ---------------------------------------------------------------- M3 = ete @ We  (3x1024 @ 1024x1024, fp32)
__global__ __launch_bounds__(256)
void compute_m3(const float* __restrict__ ete, const float* __restrict__ WeL,
                float* __restrict__ M3)
{
    __shared__ float se[3072];
    int tid = threadIdx.x;
    for (int i = tid; i < 3072; i += 256) se[i] = ete[i];
    __syncthreads();
    int j = blockIdx.x*256 + tid;
    float a0 = 0.f, a1 = 0.f, a2 = 0.f;
    for (int k = 0; k < 1024; ++k) {
        float w = WeL[(size_t)k*1024 + j];
        a0 += se[k]        * w;
        a1 += se[1024 + k] * w;
        a2 += se[2048 + k] * w;
    }
    M3[j] = a0; M3[1024 + j] = a1; M3[2048 + j] = a2;
}

// ---------------------------------------------------------------- GEMM (m97 structure + GROUP_M swizzle)
// C[M x Ntot] = A[M x K] * BT[Ntot x K]^T + bias ; store OT, rows < storeM
template <typename OT>
__global__ __launch_bounds__(256)
void gemm_bt(const bf16_t* __restrict__ A, const bf16_t* __restrict__ BT,
             const float* __restrict__ bias, OT* __restrict__ Cmat,
             int K, int Ntot, int storeM, int mtiles, int ntiles)
{
    __shared__ __align__(16) bf16_t As[128*32];
    __shared__ __align__(16) bf16_t Bs[128*32];
    const int tid  = threadIdx.x;
    const int wave = tid >> 6;
    const int lane = tid & 63;

    // Triton-style GROUP_M swizzle: 8 m-tiles x all n-tiles per group share
    // ~8.4 MB of A+B in L2 -> cuts A re-fetch (163 MB -> ~80 MB observed target)
    const int GROUP_M = 8;
    int pid = blockIdx.x;
    int in_group = GROUP_M * ntiles;
    int gid = pid / in_group;
    int first_m = gid * GROUP_M;
    int gsz = mtiles - first_m; if (gsz > GROUP_M) gsz = GROUP_M;
    int local = pid % in_group;
    const int m0 = (first_m + (local % gsz)) * 128;
    const int n0 = (local / gsz) * 128;

    const int wm = (wave & 1) * 64;
    const int wn = (wave >> 1) * 64;
    const int quad = lane >> 4;
    const int l16  = lane & 15;
    const int srow = lane >> 2;
    const int skel = (lane & 3) * 8;

    f32x4 acc[4][4];
    f32x4 zero = {0.f, 0.f, 0.f, 0.f};
#pragma unroll
    for (int i = 0; i < 4; ++i)
#pragma unroll
        for (int j = 0; j < 4; ++j) acc[i][j] = zero;

    const bf16_t* aBase = A  + (size_t)(m0 + wave*32 + srow) * K + skel;
    const bf16_t* bBase = BT + (size_t)(n0 + wave*32 + srow) * K + skel;
    bf16_t* asDst = As + (wave*32)*32;
    bf16_t* bsDst = Bs + (wave*32)*32;

    for (int k0 = 0; k0 < K; k0 += 32) {
        GLOAD_LDS16(aBase + k0,                  asDst);
        GLOAD_LDS16(aBase + (size_t)16*K + k0,   asDst + 16*32);
        GLOAD_LDS16(bBase + k0,                  bsDst);
        GLOAD_LDS16(bBase + (size_t)16*K + k0,   bsDst + 16*32);
        __syncthreads();
        bf16x8 af[4], bfr[4];
#pragma unroll
        for (int mi = 0; mi < 4; ++mi)
            af[mi] = *(const bf16x8*)(As + (wm + mi*16 + l16)*32 + quad*8);
#pragma unroll
        for (int ni = 0; ni < 4; ++ni)
            bfr[ni] = *(const bf16x8*)(Bs + (wn + ni*16 + l16)*32 + quad*8);
#pragma unroll
        for (int mi = 0; mi < 4; ++mi)
#pragma unroll
            for (int ni = 0; ni < 4; ++ni)
                acc[mi][ni] = __builtin_amdgcn_mfma_f32_16x16x32_bf16(af[mi], bfr[ni], acc[mi][ni], 0, 0, 0);
        __syncthreads();
    }

#pragma unroll
    for (int mi = 0; mi < 4; ++mi) {
#pragma unroll
        for (int ni = 0; ni < 4; ++ni) {
            int col = n0 + wn + ni*16 + l16;
            float bv = bias[col];
#pragma unroll
            for (int r = 0; r < 4; ++r) {
                int row = m0 + wm + mi*16 + quad*4 + r;
                if (row < storeM)
                    Cmat[(size_t)row * Ntot + col] = (OT)(acc[mi][ni][r] + bv);
            }
        }
    }
}

// ---------------------------------------------------------------- fused: logits + softmax + aggregate + residual
// one block per destination node; 256 threads = 8 heads x 32 threads x 4 channels
__global__ __launch_bounds__(256)
void fused_edge(const int* __restrict__ rp, const int* __restrict__ ssrc,
                const int* __restrict__ styp, const bf16_t* __restrict__ XLXR,
                const float* __restrict__ M3, const float* __restrict__ attv,
                const float* __restrict__ cbias, bf16_t* __restrict__ hbuf)
{
    int node = blockIdx.x;
    int tid = threadIdx.x;
    int c = tid * 4;
    __shared__ int s_src[256];
    __shared__ int s_typ[256];

    int b = rp[node], en = rp[node + 1];

    // own rows + per-channel constants (registers)
    bf16x4 xlv = *(const bf16x4*)(XLXR + (size_t)node*2048 + c);         // xl[node] (self-loop src)
    bf16x4 xrv = *(const bf16x4*)(XLXR + (size_t)node*2048 + 1024 + c);  // xr[node] (dst transform)
    float xr0 = (float)xrv[0], xr1 = (float)xrv[1], xr2 = (float)xrv[2], xr3 = (float)xrv[3];
    float at0 = attv[c], at1 = attv[c+1], at2 = attv[c+2], at3 = attv[c+3];
    float m3r[3][4];
#pragma unroll
    for (int t = 0; t < 3; ++t)
#pragma unroll
        for (int j = 0; j < 4; ++j) m3r[t][j] = M3[t*1024 + c + j];

    float a0 = 0.f, a1 = 0.f, a2 = 0.f, a3 = 0.f;
    float den = 0.f;
    float cnt0 = 0.f, cnt1 = 0.f, cnt2 = 0.f;

    for (int base = b; base < en; base += 256) {
        int nchunk = en - base; if (nchunk > 256) nchunk = 256;
        __syncthreads();
        if (tid < nchunk) { s_src[tid] = ssrc[base + tid]; s_typ[tid] = styp[base + tid]; }
        __syncthreads();
        for (int i = 0; i < nchunk; ++i) {
            int s = s_src[i];
            int t = s_typ[i];
            bf16x4 xs = *(const bf16x4*)(XLXR + (size_t)s*2048 + c);
            float x0 = (float)xs[0], x1 = (float)xs[1], x2 = (float)xs[2], x3 = (float)xs[3];
            float v0 = x0 + xr0 + m3r[t][0]; v0 = (v0 > 0.f) ? v0 : NEGS * v0;
            float v1 = x1 + xr1 + m3r[t][1]; v1 = (v1 > 0.f) ? v1 : NEGS * v1;
            float v2 = x2 + xr2 + m3r[t][2]; v2 = (v2 > 0.f) ? v2 : NEGS * v2;
            float v3 = x3 + xr3 + m3r[t][3]; v3 = (v3 > 0.f) ? v3 : NEGS * v3;
            float part = v0*at0 + v1*at1 + v2*at2 + v3*at3;
            part += __shfl_xor(part, 1);
            part += __shfl_xor(part, 2);
            part += __shfl_xor(part, 4);
            part += __shfl_xor(part, 8);
            part += __shfl_xor(part, 16);   // sum over the 32-lane head group
            part = fminf(fmaxf(part, -60.f), 60.f);
            float p = __expf(part);
            cnt0 += (t == 0) ? 1.f : 0.f;
            cnt1 += (t == 1) ? 1.f : 0.f;
            cnt2 += (t == 2) ? 1.f : 0.f;
            den += p;
            a0 += p * x0; a1 += p * x1; a2 += p * x2; a3 += p * x3;
        }
    }

    // self loop: edge feature = degree-weighted mean of incident edge-type rows
    float deg = cnt0 + cnt1 + cnt2;
    float inv = 1.f / fmaxf(deg, 1.f);
    float w0 = cnt0 * inv, w1 = cnt1 * inv, w2 = cnt2 * inv;
    float sx0 = (float)xlv[0], sx1 = (float)xlv[1], sx2 = (float)xlv[2], sx3 = (float)xlv[3];
    float e0 = w0*m3r[0][0] + w1*m3r[1][0] + w2*m3r[2][0];
    float e1 = w0*m3r[0][1] + w1*m3r[1][1] + w2*m3r[2][1];
    float e2 = w0*m3r[0][2] + w1*m3r[1][2] + w2*m3r[2][2];
    float e3 = w0*m3r[0][3] + w1*m3r[1][3] + w2*m3r[2][3];
    float u0 = sx0 + xr0 + e0; u0 = (u0 > 0.f) ? u0 : NEGS * u0;
    float u1 = sx1 + xr1 + e1; u1 = (u1 > 0.f) ? u1 : NEGS * u1;
    float u2 = sx2 + xr2 + e2; u2 = (u2 > 0.f) ? u2 : NEGS * u2;
    float u3 = sx3 + xr3 + e3; u3 = (u3 > 0.f) ? u3 : NEGS * u3;
    float sp = u0*at0 + u1*at1 + u2*at2 + u3*at3;
    sp += __shfl_xor(sp, 1);
    sp += __shfl_xor(sp, 2);
    sp += __shfl_xor(sp, 4);
    sp += __shfl_xor(sp, 8);
    sp += __shfl_xor(sp, 16);
    sp = fminf(fmaxf(sp, -60.f), 60.f);
    float ps = __expf(sp);
    den += ps;
    a0 += ps * sx0; a1 += ps * sx1; a2 += ps * sx2; a3 += ps * sx3;

    float invd = 1.f / den;
    bf16x4 hv = *(const bf16x4*)(hbuf + (size_t)node*1024 + c);
    const float* cb = cbias + c;
    bf16x4 outv;
    outv[0] = (bf16_t)((float)hv[0] + fmaxf(a0*invd + cb[0], 0.f));
    outv[1] = (bf16_t)((float)hv[1] + fmaxf(a1*invd + cb[1], 0.f));
    outv[2] = (bf16_t)((float)hv[2] + fmaxf(a2*invd + cb[2], 0.f));
    outv[3] = (bf16_t)((float)hv[3] + fmaxf(a3*invd + cb[3], 0.f));
    *(bf16x4*)(hbuf + (size_t)node*1024 + c) = outv;
}

// ---------------------------------------------------------------- launch
extern "C" void kernel_launch(void* const* d_in, const int* in_sizes, int n_in,
                              void* d_out, int out_size, void* d_ws, size_t ws_size,
                              hipStream_t stream)
{
    (void)in_sizes; (void)n_in; (void)out_size; (void)ws_size;
    const float* x     = (const float*)d_in[0];
    const int*   eidx  = (const int*)d_in[1];
    const int*   etype = (const int*)d_in[2];
    const int*   ntyp  = (const int*)d_in[3];
    const float* nte   = (const float*)d_in[4];
    const float* ete   = (const float*)d_in[5];
    const float* Wl    = (const float*)d_in[6];
    const float* bl    = (const float*)d_in[7];
    const float* Wr    = (const float*)d_in[8];
    const float* br    = (const float*)d_in[9];
    const float* We    = (const float*)d_in[10];
    const float* attw  = (const float*)d_in[11];
    const float* cbias = (const float*)d_in[12];
    const float* outW  = (const float*)d_in[13];
    const float* outb  = (const float*)d_in[14];
    const int* srcs = eidx;
    const int* dsts = eidx + EE;

    char* wsp = (char*)d_ws;
    size_t off = 0;
    auto carve = [&](size_t bytes) -> void* {
        void* pp = wsp + off;
        off += (bytes + 255) & ~(size_t)255;
        return pp;
    };
    bf16_t* hbuf  = (bf16_t*)carve((size_t)MPAD*1024*2);
    bf16_t* XLXR  = (bf16_t*)carve((size_t)MPAD*2048*2);
    bf16_t* WT    = (bf16_t*)carve((size_t)LL*2048*1024*2);
    bf16_t* OWT   = (bf16_t*)carve((size_t)1024*1024*2);
    float*  M3    = (float*)carve(3*1024*4);
    float*  biasb = (float*)carve(2048*4);
    int* deg    = (int*)carve((size_t)NN*4);
    int* rp     = (int*)carve((size_t)(NN+1)*4);
    int* cursor = (int*)carve((size_t)NN*4);
    int* ssrc   = (int*)carve((size_t)EE*4);
    int* styp   = (int*)carve((size_t)EE*4);
    int* incb   = (int*)carve((size_t)NN*4);
    int* bsums  = (int*)carve(64*4);

    dim3 tgrid(32, 32);
    for (int l = 0; l < LL; ++l) {
        transpose_1024<<<tgrid, 256, 0, stream>>>(Wl + (size_t)l*1024*1024, WT + (size_t)l*2048*1024);
        transpose_1024<<<tgrid, 256, 0, stream>>>(Wr + (size_t)l*1024*1024, WT + (size_t)l*2048*1024 + (size_t)1024*1024);
    }
    transpose_1024<<<tgrid, 256, 0, stream>>>(outW, OWT);

    h_init<<<5056, 256, 0, stream>>>(x, ntyp, nte, hbuf);

    zero_i32<<<40, 256, 0, stream>>>(deg, NN);
    hist_k<<<(EE + 255)/256, 256, 0, stream>>>(dsts, deg);
    scan_block<<<40, 256, 0, stream>>>(deg, incb, bsums);
    scan_sums<<<1, 64, 0, stream>>>(bsums, 40);
    finalize_rp<<<40, 256, 0, stream>>>(incb, bsums, rp);
    copy_i32<<<40, 256, 0, stream>>>(rp, cursor, NN);
    fill_csr<<<(EE + 255)/256, 256, 0, stream>>>(srcs, dsts, etype, cursor, ssrc, styp);

    for (int l = 0; l < LL; ++l) {
        pack_bias<<<8, 256, 0, stream>>>(bl + l*1024, br + l*1024, biasb, 1024, 1024);
        gemm_bt<bf16_t><<<79*16, 256, 0, stream>>>(hbuf, WT + (size_t)l*2048*1024, biasb, XLXR,
                                                   1024, 2048, MPAD, 79, 16);
        compute_m3<<<4, 256, 0, stream>>>(ete, We + (size_t)l*1024*1024, M3);
        fused_edge<<<NN, 256, 0, stream>>>(rp, ssrc, styp, XLXR, M3, attw + l*1024,
                                           cbias + l*1024, hbuf);
    }

    pack_bias<<<4, 256, 0, stream>>>(outb, outb, biasb, 1024, 0);
    gemm_bt<float><<<79*8, 256, 0, stream>>>(hbuf, OWT, biasb, (float*)d_out,
                                             1024, 1024, NN, 79, 8);
}

// Round 4
// 451.844 us; speedup vs baseline: 1.7533x; 1.3351x over previous
//
#include <hip/hip_runtime.h>
#include <hip/hip_bf16.h>
#include <stdint.h>

typedef __bf16 bf16_t;
typedef bf16_t bf16x8 __attribute__((ext_vector_type(8)));
typedef bf16_t bf16x4 __attribute__((ext_vector_type(4)));
typedef float f32x4 __attribute__((ext_vector_type(4)));

#define NN 10000
#define EE 80000
#define DD 1024
#define LL 2
#define MPAD 10112   /* 79*128 */
#define NEGS 0.2f

#define GLOAD_LDS16(g, l) \
    __builtin_amdgcn_global_load_lds((__attribute__((address_space(1))) void*)(void*)(g), \
                                     (__attribute__((address_space(3))) void*)(l), 16, 0, 0)

// ---------------------------------------------------------------- transpose fp32 -> bf16
__global__ __launch_bounds__(256)
void transpose_1024(const float* __restrict__ src, bf16_t* __restrict__ dstp)
{
    __shared__ float tile[32][33];
    int bx = blockIdx.x, by = blockIdx.y;
    int tx = threadIdx.x & 31, ty = threadIdx.x >> 5;
#pragma unroll
    for (int i = 0; i < 4; ++i)
        tile[ty + i*8][tx] = src[(size_t)(by*32 + ty + i*8)*1024 + bx*32 + tx];
    __syncthreads();
#pragma unroll
    for (int i = 0; i < 4; ++i)
        dstp[(size_t)(bx*32 + ty + i*8)*1024 + by*32 + tx] = (bf16_t)tile[tx][ty + i*8];
}

// ---------------------------------------------------------------- h init (fp32 in, bf16 out)
__global__ __launch_bounds__(256)
void h_init(const float* __restrict__ x, const int* __restrict__ ntypes,
            const float* __restrict__ nte, bf16_t* __restrict__ hbuf)
{
    size_t idx = ((size_t)blockIdx.x*256 + threadIdx.x) * 8;
    if (idx >= (size_t)MPAD*1024) return;
    int n = (int)(idx >> 10);
    int c = (int)(idx & 1023);
    bf16x8 outv;
    if (n < NN) {
        const float* xp = x + (size_t)n*1024 + c;
        int t = ntypes[n];
        const float* ep = nte + (size_t)t*1024 + c;
#pragma unroll
        for (int j = 0; j < 8; ++j) outv[j] = (bf16_t)(xp[j] + ep[j]);
    } else {
#pragma unroll
        for (int j = 0; j < 8; ++j) outv[j] = (bf16_t)0.f;
    }
    *(bf16x8*)(hbuf + idx) = outv;
}

// ---------------------------------------------------------------- CSR build
__global__ void zero_i32(int* p, int n)
{ int i = blockIdx.x*256 + threadIdx.x; if (i < n) p[i] = 0; }

__global__ void zero_f32(float* p, int n)
{ int i = blockIdx.x*256 + threadIdx.x; if (i < n) p[i] = 0.f; }

__global__ void hist_k(const int* __restrict__ dsts, int* __restrict__ deg)
{ int e = blockIdx.x*256 + threadIdx.x; if (e < EE) atomicAdd(&deg[dsts[e]], 1); }

__global__ void scan_block(const int* __restrict__ deg, int* __restrict__ inc,
                           int* __restrict__ bsums)
{
    __shared__ int sdata[256];
    int i = blockIdx.x*256 + threadIdx.x;
    int v = (i < NN) ? deg[i] : 0;
    sdata[threadIdx.x] = v;
    __syncthreads();
    for (int d = 1; d < 256; d <<= 1) {
        int t = (threadIdx.x >= d) ? sdata[threadIdx.x - d] : 0;
        __syncthreads();
        sdata[threadIdx.x] += t;
        __syncthreads();
    }
    if (i < NN) inc[i] = sdata[threadIdx.x];
    if (threadIdx.x == 255) bsums[blockIdx.x] = sdata[255];
}

__global__ void scan_sums(int* bsums, int nb)
{
    if (threadIdx.x == 0 && blockIdx.x == 0) {
        int run = 0;
        for (int i = 0; i < nb; ++i) { int v = bsums[i]; bsums[i] = run; run += v; }
    }
}

__global__ void finalize_rp(const int* __restrict__ inc, const int* __restrict__ bsums,
                            int* __restrict__ rp)
{
    int i = blockIdx.x*256 + threadIdx.x;
    if (i < NN) rp[i+1] = inc[i] + bsums[i >> 8];
    if (i == 0) rp[0] = 0;
}

__global__ void copy_i32(const int* __restrict__ a, int* __restrict__ b, int n)
{ int i = blockIdx.x*256 + threadIdx.x; if (i < n) b[i] = a[i]; }

// materialize dst-sorted src and type arrays (kills one indirection in the hot loop)
__global__ void fill_csr(const int* __restrict__ srcs, const int* __restrict__ dsts,
                         const int* __restrict__ etype, int* __restrict__ cursor,
                         int* __restrict__ sorted_src, int* __restrict__ sorted_typ)
{
    int e = blockIdx.x*256 + threadIdx.x;
    if (e < EE) {
        int d = dsts[e];
        int pos = atomicAdd(&cursor[d], 1);
        sorted_src[pos] = srcs[e];
        sorted_typ[pos] = etype[e];
    }
}

// ---------------------------------------------------------------- bias pack (fp32 -> fp32)
__global__ void pack_bias(const float* __restrict__ b1, const float* __restrict__ b2,
                          float* __restrict__ outb, int n1, int n2)
{
    int i = blockIdx.x*256 + threadIdx.x;
    if (i < n1) outb[i] = b1[i];
    else if (i < n1 + n2) outb[i] = b2[i - n1];
}

// ---------------------------------------------------------------- M3 = ete @ We  (3x1024 @ 1024x1024, fp32)
// parallel over (kchunk=64) x (j=1024); coalesced WeL reads; fp32 atomics (64/addr)
__global__ __launch_bounds__(256)
void compute_m3(const float* __restrict__ ete, const float* __restrict__ WeL,
                float* __restrict__ M3)
{
    int j  = (blockIdx.x & 3) * 256 + threadIdx.x;
    int k0 = (blockIdx.x >> 2) * 16;
    float a0 = 0.f, a1 = 0.f, a2 = 0.f;
#pragma unroll
    for (int kk = 0; kk < 16; ++kk) {
        int k = k0 + kk;
        float w = WeL[(size_t)k*1024 + j];
        a0 += ete[k]        * w;
        a1 += ete[1024 + k] * w;
        a2 += ete[2048 + k] * w;
    }
    atomicAdd(&M3[j],        a0);
    atomicAdd(&M3[1024 + j], a1);
    atomicAdd(&M3[2048 + j], a2);
}

// ---------------------------------------------------------------- GEMM (m97 structure + GROUP_M swizzle)
// C[M x Ntot] = A[M x K] * BT[Ntot x K]^T + bias ; store OT, rows < storeM
template <typename OT>
__global__ __launch_bounds__(256)
void gemm_bt(const bf16_t* __restrict__ A, const bf16_t* __restrict__ BT,
             const float* __restrict__ bias, OT* __restrict__ Cmat,
             int K, int Ntot, int storeM, int mtiles, int ntiles)
{
    __shared__ __align__(16) bf16_t As[128*32];
    __shared__ __align__(16) bf16_t Bs[128*32];
    const int tid  = threadIdx.x;
    const int wave = tid >> 6;
    const int lane = tid & 63;

    const int GROUP_M = 8;
    int pid = blockIdx.x;
    int in_group = GROUP_M * ntiles;
    int gid = pid / in_group;
    int first_m = gid * GROUP_M;
    int gsz = mtiles - first_m; if (gsz > GROUP_M) gsz = GROUP_M;
    int local = pid % in_group;
    const int m0 = (first_m + (local % gsz)) * 128;
    const int n0 = (local / gsz) * 128;

    const int wm = (wave & 1) * 64;
    const int wn = (wave >> 1) * 64;
    const int quad = lane >> 4;
    const int l16  = lane & 15;
    const int srow = lane >> 2;
    const int skel = (lane & 3) * 8;

    f32x4 acc[4][4];
    f32x4 zero = {0.f, 0.f, 0.f, 0.f};
#pragma unroll
    for (int i = 0; i < 4; ++i)
#pragma unroll
        for (int j = 0; j < 4; ++j) acc[i][j] = zero;

    const bf16_t* aBase = A  + (size_t)(m0 + wave*32 + srow) * K + skel;
    const bf16_t* bBase = BT + (size_t)(n0 + wave*32 + srow) * K + skel;
    bf16_t* asDst = As + (wave*32)*32;
    bf16_t* bsDst = Bs + (wave*32)*32;

    for (int k0 = 0; k0 < K; k0 += 32) {
        GLOAD_LDS16(aBase + k0,                  asDst);
        GLOAD_LDS16(aBase + (size_t)16*K + k0,   asDst + 16*32);
        GLOAD_LDS16(bBase + k0,                  bsDst);
        GLOAD_LDS16(bBase + (size_t)16*K + k0,   bsDst + 16*32);
        __syncthreads();
        bf16x8 af[4], bfr[4];
#pragma unroll
        for (int mi = 0; mi < 4; ++mi)
            af[mi] = *(const bf16x8*)(As + (wm + mi*16 + l16)*32 + quad*8);
#pragma unroll
        for (int ni = 0; ni < 4; ++ni)
            bfr[ni] = *(const bf16x8*)(Bs + (wn + ni*16 + l16)*32 + quad*8);
#pragma unroll
        for (int mi = 0; mi < 4; ++mi)
#pragma unroll
            for (int ni = 0; ni < 4; ++ni)
                acc[mi][ni] = __builtin_amdgcn_mfma_f32_16x16x32_bf16(af[mi], bfr[ni], acc[mi][ni], 0, 0, 0);
        __syncthreads();
    }

#pragma unroll
    for (int mi = 0; mi < 4; ++mi) {
#pragma unroll
        for (int ni = 0; ni < 4; ++ni) {
            int col = n0 + wn + ni*16 + l16;
            float bv = bias[col];
#pragma unroll
            for (int r = 0; r < 4; ++r) {
                int row = m0 + wm + mi*16 + quad*4 + r;
                if (row < storeM)
                    Cmat[(size_t)row * Ntot + col] = (OT)(acc[mi][ni][r] + bv);
            }
        }
    }
}

// ---------------------------------------------------------------- fused: logits + softmax + aggregate + residual
// one block per destination node; 256 threads = 8 heads x 32 threads x 4 channels
__global__ __launch_bounds__(256)
void fused_edge(const int* __restrict__ rp, const int* __restrict__ ssrc,
                const int* __restrict__ styp, const bf16_t* __restrict__ XLXR,
                const float* __restrict__ M3, const float* __restrict__ attv,
                const float* __restrict__ cbias, bf16_t* __restrict__ hbuf)
{
    int node = blockIdx.x;
    int tid = threadIdx.x;
    int c = tid * 4;
    __shared__ int s_src[256];
    __shared__ int s_typ[256];

    int b = rp[node], en = rp[node + 1];

    bf16x4 xlv = *(const bf16x4*)(XLXR + (size_t)node*2048 + c);
    bf16x4 xrv = *(const bf16x4*)(XLXR + (size_t)node*2048 + 1024 + c);
    float xr0 = (float)xrv[0], xr1 = (float)xrv[1], xr2 = (float)xrv[2], xr3 = (float)xrv[3];
    float at0 = attv[c], at1 = attv[c+1], at2 = attv[c+2], at3 = attv[c+3];
    float m3r[3][4];
#pragma unroll
    for (int t = 0; t < 3; ++t)
#pragma unroll
        for (int j = 0; j < 4; ++j) m3r[t][j] = M3[t*1024 + c + j];

    float a0 = 0.f, a1 = 0.f, a2 = 0.f, a3 = 0.f;
    float den = 0.f;
    float cnt0 = 0.f, cnt1 = 0.f, cnt2 = 0.f;

    for (int base = b; base < en; base += 256) {
        int nchunk = en - base; if (nchunk > 256) nchunk = 256;
        __syncthreads();
        if (tid < nchunk) { s_src[tid] = ssrc[base + tid]; s_typ[tid] = styp[base + tid]; }
        __syncthreads();
        for (int i = 0; i < nchunk; ++i) {
            int s = s_src[i];
            int t = s_typ[i];
            bf16x4 xs = *(const bf16x4*)(XLXR + (size_t)s*2048 + c);
            float x0 = (float)xs[0], x1 = (float)xs[1], x2 = (float)xs[2], x3 = (float)xs[3];
            float v0 = x0 + xr0 + m3r[t][0]; v0 = (v0 > 0.f) ? v0 : NEGS * v0;
            float v1 = x1 + xr1 + m3r[t][1]; v1 = (v1 > 0.f) ? v1 : NEGS * v1;
            float v2 = x2 + xr2 + m3r[t][2]; v2 = (v2 > 0.f) ? v2 : NEGS * v2;
            float v3 = x3 + xr3 + m3r[t][3]; v3 = (v3 > 0.f) ? v3 : NEGS * v3;
            float part = v0*at0 + v1*at1 + v2*at2 + v3*at3;
            part += __shfl_xor(part, 1);
            part += __shfl_xor(part, 2);
            part += __shfl_xor(part, 4);
            part += __shfl_xor(part, 8);
            part += __shfl_xor(part, 16);
            part = fminf(fmaxf(part, -60.f), 60.f);
            float p = __expf(part);
            cnt0 += (t == 0) ? 1.f : 0.f;
            cnt1 += (t == 1) ? 1.f : 0.f;
            cnt2 += (t == 2) ? 1.f : 0.f;
            den += p;
            a0 += p * x0; a1 += p * x1; a2 += p * x2; a3 += p * x3;
        }
    }

    float deg = cnt0 + cnt1 + cnt2;
    float inv = 1.f / fmaxf(deg, 1.f);
    float w0 = cnt0 * inv, w1 = cnt1 * inv, w2 = cnt2 * inv;
    float sx0 = (float)xlv[0], sx1 = (float)xlv[1], sx2 = (float)xlv[2], sx3 = (float)xlv[3];
    float e0 = w0*m3r[0][0] + w1*m3r[1][0] + w2*m3r[2][0];
    float e1 = w0*m3r[0][1] + w1*m3r[1][1] + w2*m3r[2][1];
    float e2 = w0*m3r[0][2] + w1*m3r[1][2] + w2*m3r[2][2];
    float e3 = w0*m3r[0][3] + w1*m3r[1][3] + w2*m3r[2][3];
    float u0 = sx0 + xr0 + e0; u0 = (u0 > 0.f) ? u0 : NEGS * u0;
    float u1 = sx1 + xr1 + e1; u1 = (u1 > 0.f) ? u1 : NEGS * u1;
    float u2 = sx2 + xr2 + e2; u2 = (u2 > 0.f) ? u2 : NEGS * u2;
    float u3 = sx3 + xr3 + e3; u3 = (u3 > 0.f) ? u3 : NEGS * u3;
    float sp = u0*at0 + u1*at1 + u2*at2 + u3*at3;
    sp += __shfl_xor(sp, 1);
    sp += __shfl_xor(sp, 2);
    sp += __shfl_xor(sp, 4);
    sp += __shfl_xor(sp, 8);
    sp += __shfl_xor(sp, 16);
    sp = fminf(fmaxf(sp, -60.f), 60.f);
    float ps = __expf(sp);
    den += ps;
    a0 += ps * sx0; a1 += ps * sx1; a2 += ps * sx2; a3 += ps * sx3;

    float invd = 1.f / den;
    bf16x4 hv = *(const bf16x4*)(hbuf + (size_t)node*1024 + c);
    const float* cb = cbias + c;
    bf16x4 outv;
    outv[0] = (bf16_t)((float)hv[0] + fmaxf(a0*invd + cb[0], 0.f));
    outv[1] = (bf16_t)((float)hv[1] + fmaxf(a1*invd + cb[1], 0.f));
    outv[2] = (bf16_t)((float)hv[2] + fmaxf(a2*invd + cb[2], 0.f));
    outv[3] = (bf16_t)((float)hv[3] + fmaxf(a3*invd + cb[3], 0.f));
    *(bf16x4*)(hbuf + (size_t)node*1024 + c) = outv;
}

// ---------------------------------------------------------------- launch
extern "C" void kernel_launch(void* const* d_in, const int* in_sizes, int n_in,
                              void* d_out, int out_size, void* d_ws, size_t ws_size,
                              hipStream_t stream)
{
    (void)in_sizes; (void)n_in; (void)out_size; (void)ws_size;
    const float* x     = (const float*)d_in[0];
    const int*   eidx  = (const int*)d_in[1];
    const int*   etype = (const int*)d_in[2];
    const int*   ntyp  = (const int*)d_in[3];
    const float* nte   = (const float*)d_in[4];
    const float* ete   = (const float*)d_in[5];
    const float* Wl    = (const float*)d_in[6];
    const float* bl    = (const float*)d_in[7];
    const float* Wr    = (const float*)d_in[8];
    const float* br    = (const float*)d_in[9];
    const float* We    = (const float*)d_in[10];
    const float* attw  = (const float*)d_in[11];
    const float* cbias = (const float*)d_in[12];
    const float* outW  = (const float*)d_in[13];
    const float* outb  = (const float*)d_in[14];
    const int* srcs = eidx;
    const int* dsts = eidx + EE;

    char* wsp = (char*)d_ws;
    size_t off = 0;
    auto carve = [&](size_t bytes) -> void* {
        void* pp = wsp + off;
        off += (bytes + 255) & ~(size_t)255;
        return pp;
    };
    bf16_t* hbuf  = (bf16_t*)carve((size_t)MPAD*1024*2);
    bf16_t* XLXR  = (bf16_t*)carve((size_t)MPAD*2048*2);
    bf16_t* WT    = (bf16_t*)carve((size_t)LL*2048*1024*2);
    bf16_t* OWT   = (bf16_t*)carve((size_t)1024*1024*2);
    float*  M3L   = (float*)carve((size_t)LL*3072*4);
    float*  biasb = (float*)carve(2048*4);
    int* deg    = (int*)carve((size_t)NN*4);
    int* rp     = (int*)carve((size_t)(NN+1)*4);
    int* cursor = (int*)carve((size_t)NN*4);
    int* ssrc   = (int*)carve((size_t)EE*4);
    int* styp   = (int*)carve((size_t)EE*4);
    int* incb   = (int*)carve((size_t)NN*4);
    int* bsums  = (int*)carve(64*4);

    dim3 tgrid(32, 32);
    for (int l = 0; l < LL; ++l) {
        transpose_1024<<<tgrid, 256, 0, stream>>>(Wl + (size_t)l*1024*1024, WT + (size_t)l*2048*1024);
        transpose_1024<<<tgrid, 256, 0, stream>>>(Wr + (size_t)l*1024*1024, WT + (size_t)l*2048*1024 + (size_t)1024*1024);
    }
    transpose_1024<<<tgrid, 256, 0, stream>>>(outW, OWT);

    h_init<<<5056, 256, 0, stream>>>(x, ntyp, nte, hbuf);

    // M3 for both layers is independent of h -> hoist out of layer loop
    zero_f32<<<(LL*3072 + 255)/256, 256, 0, stream>>>(M3L, LL*3072);
    for (int l = 0; l < LL; ++l)
        compute_m3<<<256, 256, 0, stream>>>(ete, We + (size_t)l*1024*1024, M3L + l*3072);

    zero_i32<<<40, 256, 0, stream>>>(deg, NN);
    hist_k<<<(EE + 255)/256, 256, 0, stream>>>(dsts, deg);
    scan_block<<<40, 256, 0, stream>>>(deg, incb, bsums);
    scan_sums<<<1, 64, 0, stream>>>(bsums, 40);
    finalize_rp<<<40, 256, 0, stream>>>(incb, bsums, rp);
    copy_i32<<<40, 256, 0, stream>>>(rp, cursor, NN);
    fill_csr<<<(EE + 255)/256, 256, 0, stream>>>(srcs, dsts, etype, cursor, ssrc, styp);

    for (int l = 0; l < LL; ++l) {
        pack_bias<<<8, 256, 0, stream>>>(bl + l*1024, br + l*1024, biasb, 1024, 1024);
        gemm_bt<bf16_t><<<79*16, 256, 0, stream>>>(hbuf, WT + (size_t)l*2048*1024, biasb, XLXR,
                                                   1024, 2048, MPAD, 79, 16);
        fused_edge<<<NN, 256, 0, stream>>>(rp, ssrc, styp, XLXR, M3L + l*3072, attw + l*1024,
                                           cbias + l*1024, hbuf);
    }

    pack_bias<<<4, 256, 0, stream>>>(outb, outb, biasb, 1024, 0);
    gemm_bt<float><<<79*8, 256, 0, stream>>>(hbuf, OWT, biasb, (float*)d_out,
                                             1024, 1024, NN, 79, 8);
}

// Round 5
// 417.922 us; speedup vs baseline: 1.8956x; 1.0812x over previous
//
#include <hip/hip_runtime.h>
#include <hip/hip_bf16.h>
#include <stdint.h>

typedef __bf16 bf16_t;
typedef bf16_t bf16x8 __attribute__((ext_vector_type(8)));
typedef bf16_t bf16x4 __attribute__((ext_vector_type(4)));
typedef float f32x4 __attribute__((ext_vector_type(4)));

#define NN 10000
#define EE 80000
#define DD 1024
#define LL 2
#define MPAD 10112   /* 79*128 */
#define NEGS 0.2f

#define GLOAD_LDS16(g, l) \
    __builtin_amdgcn_global_load_lds((__attribute__((address_space(1))) void*)(void*)(g), \
                                     (__attribute__((address_space(3))) void*)(l), 16, 0, 0)

// ---------------------------------------------------------------- batched transpose fp32 -> bf16
// z: 0=Wl0,1=Wr0,2=Wl1,3=Wr1 -> WT slices; 4=outW -> OWT
__global__ __launch_bounds__(256)
void transpose_batch(const float* __restrict__ Wl, const float* __restrict__ Wr,
                     const float* __restrict__ outW,
                     bf16_t* __restrict__ WT, bf16_t* __restrict__ OWT)
{
    __shared__ float tile[32][33];
    int z = blockIdx.z;
    const float* src;
    bf16_t* dstp;
    switch (z) {
        case 0: src = Wl;                       dstp = WT;                           break;
        case 1: src = Wr;                       dstp = WT + (size_t)1024*1024;       break;
        case 2: src = Wl + (size_t)1024*1024;   dstp = WT + (size_t)2*1024*1024;     break;
        case 3: src = Wr + (size_t)1024*1024;   dstp = WT + (size_t)3*1024*1024;     break;
        default: src = outW;                    dstp = OWT;                          break;
    }
    int bx = blockIdx.x, by = blockIdx.y;
    int tx = threadIdx.x & 31, ty = threadIdx.x >> 5;
#pragma unroll
    for (int i = 0; i < 4; ++i)
        tile[ty + i*8][tx] = src[(size_t)(by*32 + ty + i*8)*1024 + bx*32 + tx];
    __syncthreads();
#pragma unroll
    for (int i = 0; i < 4; ++i)
        dstp[(size_t)(bx*32 + ty + i*8)*1024 + by*32 + tx] = (bf16_t)tile[tx][ty + i*8];
}

// ---------------------------------------------------------------- h init (fp32 in, bf16 out)
__global__ __launch_bounds__(256)
void h_init(const float* __restrict__ x, const int* __restrict__ ntypes,
            const float* __restrict__ nte, bf16_t* __restrict__ hbuf)
{
    size_t idx = ((size_t)blockIdx.x*256 + threadIdx.x) * 8;
    if (idx >= (size_t)MPAD*1024) return;
    int n = (int)(idx >> 10);
    int c = (int)(idx & 1023);
    bf16x8 outv;
    if (n < NN) {
        const float* xp = x + (size_t)n*1024 + c;
        int t = ntypes[n];
        const float* ep = nte + (size_t)t*1024 + c;
#pragma unroll
        for (int j = 0; j < 8; ++j) outv[j] = (bf16_t)(xp[j] + ep[j]);
    } else {
#pragma unroll
        for (int j = 0; j < 8; ++j) outv[j] = (bf16_t)0.f;
    }
    *(bf16x8*)(hbuf + idx) = outv;
}

// ---------------------------------------------------------------- CSR build
__global__ void zero_i32(int* p, int n)
{ int i = blockIdx.x*256 + threadIdx.x; if (i < n) p[i] = 0; }

__global__ void zero_f32(float* p, int n)
{ int i = blockIdx.x*256 + threadIdx.x; if (i < n) p[i] = 0.f; }

__global__ void hist_k(const int* __restrict__ dsts, int* __restrict__ deg)
{ int e = blockIdx.x*256 + threadIdx.x; if (e < EE) atomicAdd(&deg[dsts[e]], 1); }

__global__ void scan_block(const int* __restrict__ deg, int* __restrict__ inc,
                           int* __restrict__ bsums)
{
    __shared__ int sdata[256];
    int i = blockIdx.x*256 + threadIdx.x;
    int v = (i < NN) ? deg[i] : 0;
    sdata[threadIdx.x] = v;
    __syncthreads();
    for (int d = 1; d < 256; d <<= 1) {
        int t = (threadIdx.x >= d) ? sdata[threadIdx.x - d] : 0;
        __syncthreads();
        sdata[threadIdx.x] += t;
        __syncthreads();
    }
    if (i < NN) inc[i] = sdata[threadIdx.x];
    if (threadIdx.x == 255) bsums[blockIdx.x] = sdata[255];
}

__global__ void scan_sums(int* bsums, int nb)
{
    if (threadIdx.x == 0 && blockIdx.x == 0) {
        int run = 0;
        for (int i = 0; i < nb; ++i) { int v = bsums[i]; bsums[i] = run; run += v; }
    }
}

__global__ void finalize_rp(const int* __restrict__ inc, const int* __restrict__ bsums,
                            int* __restrict__ rp)
{
    int i = blockIdx.x*256 + threadIdx.x;
    if (i < NN) rp[i+1] = inc[i] + bsums[i >> 8];
    if (i == 0) rp[0] = 0;
}

__global__ void copy_i32(const int* __restrict__ a, int* __restrict__ b, int n)
{ int i = blockIdx.x*256 + threadIdx.x; if (i < n) b[i] = a[i]; }

__global__ void fill_csr(const int* __restrict__ srcs, const int* __restrict__ dsts,
                         const int* __restrict__ etype, int* __restrict__ cursor,
                         int* __restrict__ sorted_src, int* __restrict__ sorted_typ)
{
    int e = blockIdx.x*256 + threadIdx.x;
    if (e < EE) {
        int d = dsts[e];
        int pos = atomicAdd(&cursor[d], 1);
        sorted_src[pos] = srcs[e];
        sorted_typ[pos] = etype[e];
    }
}

// ---------------------------------------------------------------- all biases in one pass
// layout: [l0: bl|br (2048)][l1: bl|br (2048)][outb (1024)]
__global__ void pack_all_bias(const float* __restrict__ bl, const float* __restrict__ br,
                              const float* __restrict__ outb, float* __restrict__ biasb)
{
    int i = blockIdx.x*256 + threadIdx.x;
    if (i < 4096) {
        int l = i >> 11, j = i & 2047;
        biasb[i] = (j < 1024) ? bl[l*1024 + j] : br[l*1024 + j - 1024];
    } else if (i < 5120) {
        biasb[i] = outb[i - 4096];
    }
}

// ---------------------------------------------------------------- M3 = ete @ We  (3x1024 @ 1024x1024, fp32)
__global__ __launch_bounds__(256)
void compute_m3(const float* __restrict__ ete, const float* __restrict__ WeL,
                float* __restrict__ M3)
{
    int j  = (blockIdx.x & 3) * 256 + threadIdx.x;
    int k0 = (blockIdx.x >> 2) * 16;
    float a0 = 0.f, a1 = 0.f, a2 = 0.f;
#pragma unroll
    for (int kk = 0; kk < 16; ++kk) {
        int k = k0 + kk;
        float w = WeL[(size_t)k*1024 + j];
        a0 += ete[k]        * w;
        a1 += ete[1024 + k] * w;
        a2 += ete[2048 + k] * w;
    }
    atomicAdd(&M3[j],        a0);
    atomicAdd(&M3[1024 + j], a1);
    atomicAdd(&M3[2048 + j], a2);
}

// ---------------------------------------------------------------- GEMM: BK=64 + XOR-swizzled LDS
// C[M x Ntot] = A[M x K] * BT[Ntot x K]^T + bias ; store OT, rows < storeM
// LDS layout: row r, 8 chunks of 8 bf16; chunk c of r stored at position c^(r&7)
// -> ds_read_b128 across l16 hits 8 distinct bank-quads (2-way alias = free, m136)
template <typename OT>
__global__ __launch_bounds__(256)
void gemm_bt(const bf16_t* __restrict__ A, const bf16_t* __restrict__ BT,
             const float* __restrict__ bias, OT* __restrict__ Cmat,
             int K, int Ntot, int storeM, int mtiles, int ntiles)
{
    __shared__ __align__(16) bf16_t As[128*64];
    __shared__ __align__(16) bf16_t Bs[128*64];
    const int tid  = threadIdx.x;
    const int wave = tid >> 6;
    const int lane = tid & 63;

    const int GROUP_M = 8;
    int pid = blockIdx.x;
    int in_group = GROUP_M * ntiles;
    int gid = pid / in_group;
    int first_m = gid * GROUP_M;
    int gsz = mtiles - first_m; if (gsz > GROUP_M) gsz = GROUP_M;
    int local = pid % in_group;
    const int m0 = (first_m + (local % gsz)) * 128;
    const int n0 = (local / gsz) * 128;

    const int wm = (wave & 1) * 64;
    const int wn = (wave >> 1) * 64;
    const int quad = lane >> 4;
    const int l16  = lane & 15;

    // staging: lane -> row (lane>>3), swizzled global chunk (lane&7)^(lane>>3)
    const int srow = lane >> 3;
    const int gcol = ((lane & 7) ^ srow) * 8;

    f32x4 acc[4][4];
    f32x4 zero = {0.f, 0.f, 0.f, 0.f};
#pragma unroll
    for (int i = 0; i < 4; ++i)
#pragma unroll
        for (int j = 0; j < 4; ++j) acc[i][j] = zero;

    const bf16_t* aBase = A  + (size_t)(m0 + wave*8 + srow) * K + gcol;
    const bf16_t* bBase = BT + (size_t)(n0 + wave*8 + srow) * K + gcol;
    bf16_t* asDst = As + wave*512;   /* wave*8 rows * 64 elems */
    bf16_t* bsDst = Bs + wave*512;

    for (int k0 = 0; k0 < K; k0 += 64) {
#pragma unroll
        for (int j = 0; j < 4; ++j)
            GLOAD_LDS16(aBase + (size_t)(j*32)*K + k0, asDst + j*2048);
#pragma unroll
        for (int j = 0; j < 4; ++j)
            GLOAD_LDS16(bBase + (size_t)(j*32)*K + k0, bsDst + j*2048);
        __syncthreads();
#pragma unroll
        for (int kk = 0; kk < 2; ++kk) {
            bf16x8 af[4], bfr[4];
#pragma unroll
            for (int mi = 0; mi < 4; ++mi) {
                int row = wm + mi*16 + l16;
                int ch  = ((kk*4 + quad) ^ (row & 7)) * 8;
                af[mi] = *(const bf16x8*)(As + row*64 + ch);
            }
#pragma unroll
            for (int ni = 0; ni < 4; ++ni) {
                int row = wn + ni*16 + l16;
                int ch  = ((kk*4 + quad) ^ (row & 7)) * 8;
                bfr[ni] = *(const bf16x8*)(Bs + row*64 + ch);
            }
#pragma unroll
            for (int mi = 0; mi < 4; ++mi)
#pragma unroll
                for (int ni = 0; ni < 4; ++ni)
                    acc[mi][ni] = __builtin_amdgcn_mfma_f32_16x16x32_bf16(af[mi], bfr[ni], acc[mi][ni], 0, 0, 0);
        }
        __syncthreads();
    }

#pragma unroll
    for (int mi = 0; mi < 4; ++mi) {
#pragma unroll
        for (int ni = 0; ni < 4; ++ni) {
            int col = n0 + wn + ni*16 + l16;
            float bv = bias[col];
#pragma unroll
            for (int r = 0; r < 4; ++r) {
                int row = m0 + wm + mi*16 + quad*4 + r;
                if (row < storeM)
                    Cmat[(size_t)row * Ntot + col] = (OT)(acc[mi][ni][r] + bv);
            }
        }
    }
}

// ---------------------------------------------------------------- fused: logits + softmax + aggregate + residual
__global__ __launch_bounds__(256)
void fused_edge(const int* __restrict__ rp, const int* __restrict__ ssrc,
                const int* __restrict__ styp, const bf16_t* __restrict__ XLXR,
                const float* __restrict__ M3, const float* __restrict__ attv,
                const float* __restrict__ cbias, bf16_t* __restrict__ hbuf)
{
    int node = blockIdx.x;
    int tid = threadIdx.x;
    int c = tid * 4;
    __shared__ int s_src[256];
    __shared__ int s_typ[256];

    int b = rp[node], en = rp[node + 1];

    bf16x4 xlv = *(const bf16x4*)(XLXR + (size_t)node*2048 + c);
    bf16x4 xrv = *(const bf16x4*)(XLXR + (size_t)node*2048 + 1024 + c);
    float xr0 = (float)xrv[0], xr1 = (float)xrv[1], xr2 = (float)xrv[2], xr3 = (float)xrv[3];
    float at0 = attv[c], at1 = attv[c+1], at2 = attv[c+2], at3 = attv[c+3];
    float m3r[3][4];
#pragma unroll
    for (int t = 0; t < 3; ++t)
#pragma unroll
        for (int j = 0; j < 4; ++j) m3r[t][j] = M3[t*1024 + c + j];

    float a0 = 0.f, a1 = 0.f, a2 = 0.f, a3 = 0.f;
    float den = 0.f;
    float cnt0 = 0.f, cnt1 = 0.f, cnt2 = 0.f;

    for (int base = b; base < en; base += 256) {
        int nchunk = en - base; if (nchunk > 256) nchunk = 256;
        __syncthreads();
        if (tid < nchunk) { s_src[tid] = ssrc[base + tid]; s_typ[tid] = styp[base + tid]; }
        __syncthreads();
        for (int i = 0; i < nchunk; ++i) {
            int s = s_src[i];
            int t = s_typ[i];
            bf16x4 xs = *(const bf16x4*)(XLXR + (size_t)s*2048 + c);
            float x0 = (float)xs[0], x1 = (float)xs[1], x2 = (float)xs[2], x3 = (float)xs[3];
            float v0 = x0 + xr0 + m3r[t][0]; v0 = (v0 > 0.f) ? v0 : NEGS * v0;
            float v1 = x1 + xr1 + m3r[t][1]; v1 = (v1 > 0.f) ? v1 : NEGS * v1;
            float v2 = x2 + xr2 + m3r[t][2]; v2 = (v2 > 0.f) ? v2 : NEGS * v2;
            float v3 = x3 + xr3 + m3r[t][3]; v3 = (v3 > 0.f) ? v3 : NEGS * v3;
            float part = v0*at0 + v1*at1 + v2*at2 + v3*at3;
            part += __shfl_xor(part, 1);
            part += __shfl_xor(part, 2);
            part += __shfl_xor(part, 4);
            part += __shfl_xor(part, 8);
            part += __shfl_xor(part, 16);
            part = fminf(fmaxf(part, -60.f), 60.f);
            float p = __expf(part);
            cnt0 += (t == 0) ? 1.f : 0.f;
            cnt1 += (t == 1) ? 1.f : 0.f;
            cnt2 += (t == 2) ? 1.f : 0.f;
            den += p;
            a0 += p * x0; a1 += p * x1; a2 += p * x2; a3 += p * x3;
        }
    }

    float deg = cnt0 + cnt1 + cnt2;
    float inv = 1.f / fmaxf(deg, 1.f);
    float w0 = cnt0 * inv, w1 = cnt1 * inv, w2 = cnt2 * inv;
    float sx0 = (float)xlv[0], sx1 = (float)xlv[1], sx2 = (float)xlv[2], sx3 = (float)xlv[3];
    float e0 = w0*m3r[0][0] + w1*m3r[1][0] + w2*m3r[2][0];
    float e1 = w0*m3r[0][1] + w1*m3r[1][1] + w2*m3r[2][1];
    float e2 = w0*m3r[0][2] + w1*m3r[1][2] + w2*m3r[2][2];
    float e3 = w0*m3r[0][3] + w1*m3r[1][3] + w2*m3r[2][3];
    float u0 = sx0 + xr0 + e0; u0 = (u0 > 0.f) ? u0 : NEGS * u0;
    float u1 = sx1 + xr1 + e1; u1 = (u1 > 0.f) ? u1 : NEGS * u1;
    float u2 = sx2 + xr2 + e2; u2 = (u2 > 0.f) ? u2 : NEGS * u2;
    float u3 = sx3 + xr3 + e3; u3 = (u3 > 0.f) ? u3 : NEGS * u3;
    float sp = u0*at0 + u1*at1 + u2*at2 + u3*at3;
    sp += __shfl_xor(sp, 1);
    sp += __shfl_xor(sp, 2);
    sp += __shfl_xor(sp, 4);
    sp += __shfl_xor(sp, 8);
    sp += __shfl_xor(sp, 16);
    sp = fminf(fmaxf(sp, -60.f), 60.f);
    float ps = __expf(sp);
    den += ps;
    a0 += ps * sx0; a1 += ps * sx1; a2 += ps * sx2; a3 += ps * sx3;

    float invd = 1.f / den;
    bf16x4 hv = *(const bf16x4*)(hbuf + (size_t)node*1024 + c);
    const float* cb = cbias + c;
    bf16x4 outv;
    outv[0] = (bf16_t)((float)hv[0] + fmaxf(a0*invd + cb[0], 0.f));
    outv[1] = (bf16_t)((float)hv[1] + fmaxf(a1*invd + cb[1], 0.f));
    outv[2] = (bf16_t)((float)hv[2] + fmaxf(a2*invd + cb[2], 0.f));
    outv[3] = (bf16_t)((float)hv[3] + fmaxf(a3*invd + cb[3], 0.f));
    *(bf16x4*)(hbuf + (size_t)node*1024 + c) = outv;
}

// ---------------------------------------------------------------- launch
extern "C" void kernel_launch(void* const* d_in, const int* in_sizes, int n_in,
                              void* d_out, int out_size, void* d_ws, size_t ws_size,
                              hipStream_t stream)
{
    (void)in_sizes; (void)n_in; (void)out_size; (void)ws_size;
    const float* x     = (const float*)d_in[0];
    const int*   eidx  = (const int*)d_in[1];
    const int*   etype = (const int*)d_in[2];
    const int*   ntyp  = (const int*)d_in[3];
    const float* nte   = (const float*)d_in[4];
    const float* ete   = (const float*)d_in[5];
    const float* Wl    = (const float*)d_in[6];
    const float* bl    = (const float*)d_in[7];
    const float* Wr    = (const float*)d_in[8];
    const float* br    = (const float*)d_in[9];
    const float* We    = (const float*)d_in[10];
    const float* attw  = (const float*)d_in[11];
    const float* cbias = (const float*)d_in[12];
    const float* outW  = (const float*)d_in[13];
    const float* outb  = (const float*)d_in[14];
    const int* srcs = eidx;
    const int* dsts = eidx + EE;

    char* wsp = (char*)d_ws;
    size_t off = 0;
    auto carve = [&](size_t bytes) -> void* {
        void* pp = wsp + off;
        off += (bytes + 255) & ~(size_t)255;
        return pp;
    };
    bf16_t* hbuf  = (bf16_t*)carve((size_t)MPAD*1024*2);
    bf16_t* XLXR  = (bf16_t*)carve((size_t)MPAD*2048*2);
    bf16_t* WT    = (bf16_t*)carve((size_t)LL*2048*1024*2);
    bf16_t* OWT   = (bf16_t*)carve((size_t)1024*1024*2);
    float*  M3L   = (float*)carve((size_t)LL*3072*4);
    float*  biasb = (float*)carve(5120*4);
    int* deg    = (int*)carve((size_t)NN*4);
    int* rp     = (int*)carve((size_t)(NN+1)*4);
    int* cursor = (int*)carve((size_t)NN*4);
    int* ssrc   = (int*)carve((size_t)EE*4);
    int* styp   = (int*)carve((size_t)EE*4);
    int* incb   = (int*)carve((size_t)NN*4);
    int* bsums  = (int*)carve(64*4);

    transpose_batch<<<dim3(32, 32, 5), 256, 0, stream>>>(Wl, Wr, outW, WT, OWT);
    h_init<<<5056, 256, 0, stream>>>(x, ntyp, nte, hbuf);
    pack_all_bias<<<20, 256, 0, stream>>>(bl, br, outb, biasb);

    zero_f32<<<(LL*3072 + 255)/256, 256, 0, stream>>>(M3L, LL*3072);
    for (int l = 0; l < LL; ++l)
        compute_m3<<<256, 256, 0, stream>>>(ete, We + (size_t)l*1024*1024, M3L + l*3072);

    zero_i32<<<40, 256, 0, stream>>>(deg, NN);
    hist_k<<<(EE + 255)/256, 256, 0, stream>>>(dsts, deg);
    scan_block<<<40, 256, 0, stream>>>(deg, incb, bsums);
    scan_sums<<<1, 64, 0, stream>>>(bsums, 40);
    finalize_rp<<<40, 256, 0, stream>>>(incb, bsums, rp);
    copy_i32<<<40, 256, 0, stream>>>(rp, cursor, NN);
    fill_csr<<<(EE + 255)/256, 256, 0, stream>>>(srcs, dsts, etype, cursor, ssrc, styp);

    for (int l = 0; l < LL; ++l) {
        gemm_bt<bf16_t><<<79*16, 256, 0, stream>>>(hbuf, WT + (size_t)l*2048*1024,
                                                   biasb + l*2048, XLXR,
                                                   1024, 2048, MPAD, 79, 16);
        fused_edge<<<NN, 256, 0, stream>>>(rp, ssrc, styp, XLXR, M3L + l*3072, attw + l*1024,
                                           cbias + l*1024, hbuf);
    }

    gemm_bt<float><<<79*8, 256, 0, stream>>>(hbuf, OWT, biasb + 4096, (float*)d_out,
                                             1024, 1024, NN, 79, 8);
}